// Round 7
// baseline (541.029 us; speedup 1.0000x reference)
//
#include <hip/hip_runtime.h>
#include <string.h>

#define NN 100000
#define EE 1600000
#define NF 256
#define NH 128

#define BK 98        // buckets of 1024 nodes: ceil(100000/1024)
#define BNODE 1024
#define CHUNK 4096
#define NCHUNK ((EE + CHUNK - 1) / CHUNK)  // 391
#define CAP 24576    // P2 LDS staging capacity (mean 16327, std ~128)

typedef unsigned int u32;
typedef unsigned short u16;
typedef __attribute__((ext_vector_type(8))) short short8;
typedef __attribute__((ext_vector_type(4))) float f32x4;

static __device__ __forceinline__ u16 f2bf(float f) {
  u32 u = __float_as_uint(f);
  u32 r = (u + 0x7FFFu + ((u >> 16) & 1u)) >> 16;
  return (u16)r;
}
static __device__ __forceinline__ float bflo(u32 u) { return __uint_as_float(u << 16); }
static __device__ __forceinline__ float bfhi(u32 u) { return __uint_as_float(u & 0xFFFF0000u); }

// ---------------- P0: bucket histogram ----------------
__global__ __launch_bounds__(256) void k_p0(const int* __restrict__ col,
                                            u32* __restrict__ bcnt) {
  __shared__ u32 hist[BK];
  int t = threadIdx.x;
  if (t < BK) hist[t] = 0;
  __syncthreads();
  int e0 = blockIdx.x * CHUNK;
  int e1 = min(e0 + CHUNK, EE);
  for (int e = e0 + t; e < e1; e += 256) {
    u32 d = (u32)col[e];
    atomicAdd(&hist[d >> 10], 1u);
  }
  __syncthreads();
  if (t < BK && hist[t]) atomicAdd(&bcnt[t], hist[t]);
}

// ---------------- bucket scan (tiny) ----------------
__global__ void k_bscan(const u32* __restrict__ bcnt, u32* __restrict__ bbase,
                        u32* __restrict__ gcur, u32* __restrict__ off) {
  if (threadIdx.x == 0) {
    u32 s = 0;
    for (int b = 0; b < BK; b++) { bbase[b] = s; gcur[b] = s; s += bcnt[b]; }
    off[NN] = EE;
  }
}

// ---------------- P1: counting-sort edges into buckets (run-writes) --------
__global__ __launch_bounds__(256) void k_p1(const int* __restrict__ row,
                                            const int* __restrict__ col,
                                            u32* __restrict__ gcur,
                                            u32* __restrict__ binned) {
  __shared__ u32 keybuf[CHUNK];
  __shared__ unsigned char bktbuf[CHUNK];
  __shared__ u32 hist[BK], lstart[BK], lofs[BK], gb[BK];
  int t = threadIdx.x;
  if (t < BK) hist[t] = 0;
  __syncthreads();
  int e0 = blockIdx.x * CHUNK;
  int n = min(CHUNK, EE - e0);
  for (int i = t; i < n; i += 256) {
    u32 d = (u32)col[e0 + i];
    atomicAdd(&hist[d >> 10], 1u);
  }
  __syncthreads();
  if (t == 0) {
    u32 s = 0;
    for (int b = 0; b < BK; b++) { lstart[b] = s; lofs[b] = s; s += hist[b]; }
  }
  __syncthreads();
  if (t < BK && hist[t]) gb[t] = atomicAdd(&gcur[t], hist[t]);
  __syncthreads();
  for (int i = t; i < n; i += 256) {
    u32 d = (u32)col[e0 + i];
    u32 s = (u32)row[e0 + i];
    u32 b = d >> 10;
    u32 p = atomicAdd(&lofs[b], 1u);
    keybuf[p] = ((d & 1023u) << 17) | s;
    bktbuf[p] = (unsigned char)b;
  }
  __syncthreads();
  for (int i = t; i < n; i += 256) {
    u32 b = bktbuf[i];
    binned[gb[b] + ((u32)i - lstart[b])] = keybuf[i];
  }
}

// ---------------- P2: per-bucket counting sort in LDS ----------------
__global__ __launch_bounds__(1024) void k_p2(const u32* __restrict__ binned,
                                             const u32* __restrict__ bbase,
                                             const u32* __restrict__ bcnt,
                                             u32* __restrict__ off,
                                             float* __restrict__ dinv,
                                             int* __restrict__ csr) {
  __shared__ u32 hist[BNODE];
  __shared__ u32 loff[BNODE];
  __shared__ u32 cur[BNODE];
  __shared__ u32 stage[CAP];
  int b = blockIdx.x, t = threadIdx.x;
  u32 base = bbase[b], cnt = bcnt[b];
  hist[t] = 0;
  __syncthreads();
  for (u32 i = t; i < cnt; i += BNODE) {
    u32 key = binned[base + i];
    atomicAdd(&hist[key >> 17], 1u);
  }
  __syncthreads();
  u32 v = hist[t];
  loff[t] = v;
  __syncthreads();
  for (int d = 1; d < BNODE; d <<= 1) {
    u32 x = loff[t];
    u32 y = (t >= d) ? loff[t - d] : 0u;
    __syncthreads();
    loff[t] = x + y;
    __syncthreads();
  }
  u32 ex = loff[t] - v;
  cur[t] = ex;
  int g = b * BNODE + t;
  if (g < NN) {
    off[g] = base + ex;
    dinv[g] = rsqrtf((float)(v + 1u));
  }
  __syncthreads();
  if (cnt <= CAP) {
    for (u32 i = t; i < cnt; i += BNODE) {
      u32 key = binned[base + i];
      u32 p = atomicAdd(&cur[key >> 17], 1u);
      stage[p] = key & 0x1FFFFu;
    }
    __syncthreads();
    for (u32 i = t; i < cnt; i += BNODE) csr[base + i] = (int)stage[i];
  } else {
    for (u32 i = t; i < cnt; i += BNODE) {
      u32 key = binned[base + i];
      u32 p = atomicAdd(&cur[key >> 17], 1u);
      csr[base + p] = (int)(key & 0x1FFFFu);
    }
  }
}

// ---------------- spectral norm chain + fused Wt transpose ----------------
__global__ void k_gram(const float* __restrict__ W, float* __restrict__ B,
                       float* __restrict__ M0, float* __restrict__ tr,
                       u16* __restrict__ Wt) {
  __shared__ float wi[NF];
  int i = blockIdx.x, j = threadIdx.x;
  for (int k = j; k < NF; k += NH) wi[k] = W[k * NH + i];
  __syncthreads();
  for (int k = j; k < NF; k += NH) Wt[i * NF + k] = f2bf(wi[k]);
  float acc = 0.f;
  for (int k = 0; k < NF; k++) acc += wi[k] * W[k * NH + j];
  B[i * NH + j] = acc;
  M0[i * NH + j] = acc;
  if (i == j) atomicAdd(tr, acc);
}

__global__ void k_sq(const float* __restrict__ Min, float* __restrict__ Mout,
                     const float* __restrict__ tr_in, float* __restrict__ tr_out) {
  __shared__ float ri[NH];
  int i = blockIdx.x, j = threadIdx.x;
  ri[j] = Min[i * NH + j];
  __syncthreads();
  float acc = 0.f;
  for (int k = 0; k < NH; k++) acc += ri[k] * Min[k * NH + j];
  float it = 1.0f / tr_in[0];
  acc *= it * it;
  Mout[i * NH + j] = acc;
  if (i == j) atomicAdd(tr_out, acc);
}

__global__ void k_final(const float* __restrict__ M, const float* __restrict__ B,
                        float* __restrict__ sig) {
  __shared__ float u[NH], red[NH];
  __shared__ int idx[NH];
  int t = threadIdx.x;
  red[t] = M[t * NH + t];
  idx[t] = t;
  __syncthreads();
  for (int d = 64; d > 0; d >>= 1) {
    if (t < d && red[t + d] > red[t]) { red[t] = red[t + d]; idx[t] = idx[t + d]; }
    __syncthreads();
  }
  int jm = idx[0];
  __syncthreads();
  u[t] = M[t * NH + jm];
  __syncthreads();
  float acc = 0.f;
  for (int k = 0; k < NH; k++) acc += B[t * NH + k] * u[k];
  red[t] = u[t] * acc;
  __syncthreads();
  for (int d = 64; d > 0; d >>= 1) { if (t < d) red[t] += red[t + d]; __syncthreads(); }
  float numer = red[0];
  __syncthreads();
  red[t] = u[t] * u[t];
  __syncthreads();
  for (int d = 64; d > 0; d >>= 1) { if (t < d) red[t] += red[t + d]; __syncthreads(); }
  float denom = red[0];
  if (t == 0) sig[0] = rsqrtf(numer / denom);  // 1/sigma
}

// ---------------- MFMA GEMM, barrier-free; sliced hs output ----------------
// hs layout: [8 slices][NN rows][16 cols] bf16 (slice stride NN*16 u16 = 3.2MB)
__global__ __launch_bounds__(256) void k_mfma(const float* __restrict__ x,
                                              const u16* __restrict__ Wt,
                                              const float* __restrict__ dinv,
                                              u16* __restrict__ hs) {
  __shared__ __align__(16) u16 tile[128 * 128];
  int t = threadIdx.x;
  int l = t & 63, w = t >> 6;
  int row0 = blockIdx.x * 128;
  int lr = l & 15;
  int lk = (l >> 4) * 8;

  long arow[2];
#pragma unroll
  for (int m = 0; m < 2; m++) {
    int r = row0 + w * 32 + m * 16 + lr;
    arow[m] = (long)((r < NN) ? r : (NN - 1)) * NF;
  }

  f32x4 acc[2][8] = {};
  short8 afr[2][2];

#define LOADA(ph, k0)                                                        \
  {                                                                          \
    _Pragma("unroll") for (int m = 0; m < 2; m++) {                          \
      f32x4 p0 = __builtin_nontemporal_load((const f32x4*)&x[arow[m] + (k0) + lk]);     \
      f32x4 p1 = __builtin_nontemporal_load((const f32x4*)&x[arow[m] + (k0) + lk + 4]); \
      u32 wd[4];                                                             \
      wd[0] = (u32)f2bf(p0[0]) | ((u32)f2bf(p0[1]) << 16);                   \
      wd[1] = (u32)f2bf(p0[2]) | ((u32)f2bf(p0[3]) << 16);                   \
      wd[2] = (u32)f2bf(p1[0]) | ((u32)f2bf(p1[1]) << 16);                   \
      wd[3] = (u32)f2bf(p1[2]) | ((u32)f2bf(p1[3]) << 16);                   \
      afr[ph][m] = *(short8*)wd;                                             \
    }                                                                        \
  }

  LOADA(0, 0)
#pragma unroll
  for (int ks = 0; ks < 8; ks++) {
    int cur = ks & 1, nxt = cur ^ 1;
    if (ks < 7) LOADA(nxt, (ks + 1) * 32)
    short8 bfr[8];
#pragma unroll
    for (int n = 0; n < 8; n++)
      bfr[n] = *(const short8*)&Wt[(n * 16 + lr) * NF + ks * 32 + lk];
#pragma unroll
    for (int m = 0; m < 2; m++)
#pragma unroll
      for (int n = 0; n < 8; n++)
        acc[m][n] = __builtin_amdgcn_mfma_f32_16x16x32_bf16(afr[cur][m], bfr[n], acc[m][n], 0, 0, 0);
  }
#undef LOADA

  // epilogue: scale, cvt, repack via LDS, store sliced layout
#pragma unroll
  for (int m = 0; m < 2; m++) {
    int rbl = w * 32 + m * 16 + (l >> 4) * 4;
    float dv[4];
#pragma unroll
    for (int g = 0; g < 4; g++) {
      int r = row0 + rbl + g;
      dv[g] = (r < NN) ? dinv[r] : 0.f;
    }
#pragma unroll
    for (int n = 0; n < 8; n++)
#pragma unroll
      for (int g = 0; g < 4; g++)
        tile[(rbl + g) * 128 + n * 16 + lr] = f2bf(acc[m][n][g] * dv[g]);
  }
  __syncthreads();
  const uint4* tl = (const uint4*)tile;
#pragma unroll
  for (int k = 0; k < 8; k++) {
    int u = t + k * 256;      // uint4 idx: row r = u>>4, c8 = u&15 (8 cols each)
    int r = u >> 4;
    int c8 = u & 15;
    int s = c8 >> 1, hf = c8 & 1;
    if (row0 + r < NN)
      *(uint4*)&hs[((size_t)s * NN + row0 + r) * 16 + hf * 8] = tl[u];
  }
}

// ---------------- sliced gather: block=(bucket, slice->XCD) ----------------
// Wave per dst; 8 lanes x 8 edge-groups; slice (3.2MB) stays L2-resident on
// its XCD. csr nontemporal (8x re-read, don't pollute L2); out nontemporal.
__global__ __launch_bounds__(512) void k_gather(const u16* __restrict__ hs,
                                                const int* __restrict__ csr,
                                                const u32* __restrict__ off,
                                                const float* __restrict__ dinv,
                                                const float* __restrict__ b,
                                                const float* __restrict__ pa,
                                                const float* __restrict__ sig,
                                                float* __restrict__ out) {
  int s = blockIdx.x & 7;   // slice; round-robin blocks -> same XCD per slice
  int j = blockIdx.x >> 3;  // bucket
  int t = threadIdx.x;
  int w = t >> 6, l = t & 63;
  int eg = l >> 3, c = l & 7;  // edge-group, u32-col (2 bf16) within slice
  const u32* hs32 = (const u32*)hs + (size_t)s * NN * 8;
  float sg = sig[0];
  float a = pa[0];
  float2 bb = *(const float2*)&b[s * 16 + 2 * (l & 7)];
  int n0 = j * 1024 + w * 128;
  for (int nl = 0; nl < 128; nl++) {
    int n = n0 + nl;
    if (n >= NN) break;
    u32 s0 = off[n], s1 = off[n + 1];
    float ax = 0.f, ay = 0.f;
    if (eg == 0) {  // self-loop term, counted once
      u32 u = hs32[(size_t)n * 8 + c];
      ax = bflo(u); ay = bfhi(u);
    }
    for (u32 e = s0 + eg; e < s1; e += 8) {
      int src = __builtin_nontemporal_load(&csr[e]);
      u32 u = hs32[(size_t)src * 8 + c];
      ax += bflo(u); ay += bfhi(u);
    }
    ax += __shfl_xor(ax, 8);  ay += __shfl_xor(ay, 8);
    ax += __shfl_xor(ax, 16); ay += __shfl_xor(ay, 16);
    ax += __shfl_xor(ax, 32); ay += __shfl_xor(ay, 32);
    if (l < 8) {
      float dv = dinv[n] * sg;
      float v0 = ax * dv + bb.x;
      float v1 = ay * dv + bb.y;
      float2 o;
      o.x = v0 > 0.f ? v0 : a * v0;
      o.y = v1 > 0.f ? v1 : a * v1;
      double od;
      memcpy(&od, &o, 8);
      __builtin_nontemporal_store(od, (double*)&out[(size_t)n * NH + s * 16 + 2 * l]);
    }
  }
}

// ---------------- launch ----------------
extern "C" void kernel_launch(void* const* d_in, const int* in_sizes, int n_in,
                              void* d_out, int out_size, void* d_ws, size_t ws_size,
                              hipStream_t stream) {
  const float* x = (const float*)d_in[0];
  const int* ei = (const int*)d_in[1];
  const float* W = (const float*)d_in[2];
  const float* b = (const float*)d_in[3];
  const float* pa = (const float*)d_in[4];
  float* out = (float*)d_out;
  const int* row = ei;
  const int* col = ei + EE;

  char* base = (char*)d_ws;
  size_t o = 0;
  auto alloc = [&](size_t bytes) -> void* {
    void* p = base + o;
    o += (bytes + 63) & ~(size_t)63;
    return p;
  };
  // --- zeroed region ---
  u32* bcnt = (u32*)alloc(BK * 4);
  float* tr = (float*)alloc(16 * 4);
  float* sig = (float*)alloc(64);
  size_t zbytes = o;
  // --- rest ---
  u32* bbase = (u32*)alloc(BK * 4);
  u32* gcur = (u32*)alloc(BK * 4);
  float* dinv = (float*)alloc((size_t)NN * 4);
  u32* off = (u32*)alloc((size_t)(NN + 4) * 4);
  u32* binned = (u32*)alloc((size_t)EE * 4);
  int* csr = (int*)alloc((size_t)EE * 4);
  float* B = (float*)alloc((size_t)NH * NH * 4);
  float* M0 = (float*)alloc((size_t)NH * NH * 4);
  float* M1 = (float*)alloc((size_t)NH * NH * 4);
  u16* Wt = (u16*)alloc((size_t)NF * NH * 2);
  u16* hs = (u16*)alloc((size_t)NN * NH * 2);
  (void)ws_size; (void)in_sizes; (void)n_in; (void)out_size;

  hipMemsetAsync(bcnt, 0, zbytes, stream);

  k_p0<<<NCHUNK, 256, 0, stream>>>(col, bcnt);
  k_bscan<<<1, 64, 0, stream>>>(bcnt, bbase, gcur, off);
  k_p1<<<NCHUNK, 256, 0, stream>>>(row, col, gcur, binned);
  k_p2<<<BK, BNODE, 0, stream>>>(binned, bbase, bcnt, off, dinv, csr);

  k_gram<<<NH, NH, 0, stream>>>(W, B, M0, tr, Wt);
  float* Ms = M0;
  float* Md = M1;
  for (int s = 0; s < 8; s++) {
    k_sq<<<NH, NH, 0, stream>>>(Ms, Md, tr + s, tr + s + 1);
    float* tmp = Ms; Ms = Md; Md = tmp;
  }
  k_final<<<1, NH, 0, stream>>>(Ms, B, sig);

  k_mfma<<<(NN + 127) / 128, 256, 0, stream>>>(x, Wt, dinv, hs);
  k_gather<<<BK * 8, 512, 0, stream>>>(hs, csr, off, dinv, b, pa, sig, out);
}